// Round 4
// baseline (738.188 us; speedup 1.0000x reference)
//
#include <hip/hip_runtime.h>

typedef __attribute__((ext_vector_type(8))) short short8;
typedef __attribute__((ext_vector_type(4))) float floatx4;

__device__ inline unsigned short f2bf(float f) {
    union { float f; unsigned int i; } c; c.f = f;
    unsigned int x = c.i;
    unsigned int r = x + 0x7fffu + ((x >> 16) & 1u);
    return (unsigned short)(r >> 16);
}
__device__ inline short8 cvt8(float4 a, float4 b) {
    short8 v;
    v[0] = (short)f2bf(a.x); v[1] = (short)f2bf(a.y);
    v[2] = (short)f2bf(a.z); v[3] = (short)f2bf(a.w);
    v[4] = (short)f2bf(b.x); v[5] = (short)f2bf(b.y);
    v[6] = (short)f2bf(b.z); v[7] = (short)f2bf(b.w);
    return v;
}

// C = A[M,K] @ W[N,K]^T + bias[N]; A is f32 (A_F32) or bf16; W,bias f32; MFMA bf16, acc fp32
// mode 0: out bf16 [b][h][s][d]; mode 1: out bf16 [b][h][d][s]; mode 2: out f32 [m][n]
template <bool A_F32>
__global__ __launch_bounds__(256, 2)
void gemm_bt(const void* __restrict__ Av,
             const float* __restrict__ W,
             const float* __restrict__ bias,
             void* __restrict__ outv,
             int M, int N, int K, int mode)
{
    __shared__ __align__(16) unsigned short As[128 * 64]; // LDS[row][slot]=glob[row][slot^(row&7)]
    __shared__ __align__(16) unsigned short Bs[128 * 64];
    const int t = threadIdx.x, lane = t & 63, wv = t >> 6;
    const int quad = lane >> 4, l16 = lane & 15;
    const int m0 = blockIdx.x * 128, n0 = blockIdx.y * 128;
    const int wm = (wv >> 1) * 64, wn = (wv & 1) * 64;

    floatx4 acc[4][4] = {};

    for (int k0 = 0; k0 < K; k0 += 64) {
#pragma unroll
        for (int s = 0; s < 4; s++) {
            int e = t + s * 256;
            int row = e >> 3, c = e & 7;
            int slot = c ^ (row & 7);
            if (A_F32) {
                const float* ap = &((const float*)Av)[(size_t)(m0 + row) * K + k0 + c * 8];
                *(short8*)&As[row * 64 + slot * 8] =
                    cvt8(*(const float4*)ap, *(const float4*)(ap + 4));
            } else {
                *(short8*)&As[row * 64 + slot * 8] =
                    *(const short8*)&((const unsigned short*)Av)[(size_t)(m0 + row) * K + k0 + c * 8];
            }
            const float* wp = &W[(size_t)(n0 + row) * K + k0 + c * 8];
            *(short8*)&Bs[row * 64 + slot * 8] =
                cvt8(*(const float4*)wp, *(const float4*)(wp + 4));
        }
        __syncthreads();

        short8 af[4][2], bfr[4][2];
#pragma unroll
        for (int i = 0; i < 4; i++)
#pragma unroll
            for (int c = 0; c < 2; c++)
                af[i][c] = *(const short8*)&As[(wm + i * 16 + l16) * 64 + (((c * 4 + quad) ^ (l16 & 7)) * 8)];
#pragma unroll
        for (int j = 0; j < 4; j++)
#pragma unroll
            for (int c = 0; c < 2; c++)
                bfr[j][c] = *(const short8*)&Bs[(wn + j * 16 + l16) * 64 + (((c * 4 + quad) ^ (l16 & 7)) * 8)];

#pragma unroll
        for (int c = 0; c < 2; c++)
#pragma unroll
            for (int i = 0; i < 4; i++)
#pragma unroll
                for (int j = 0; j < 4; j++)
                    acc[i][j] = __builtin_amdgcn_mfma_f32_16x16x32_bf16(af[i][c], bfr[j][c], acc[i][j], 0, 0, 0);
        __syncthreads();
    }

    // C/D layout: col=lane&15, row=quad*4+reg
#pragma unroll
    for (int i = 0; i < 4; i++) {
#pragma unroll
        for (int j = 0; j < 4; j++) {
            int n = n0 + wn + j * 16 + l16;
            float bv = bias[n];
#pragma unroll
            for (int r = 0; r < 4; r++) {
                int m = m0 + wm + i * 16 + quad * 4 + r;
                float v = acc[i][j][r] + bv;
                if (mode == 2) {
                    ((float*)outv)[(size_t)m * N + n] = v;
                } else {
                    int b = m >> 11, s = m & 2047, h = n >> 6, d = n & 63;
                    size_t idx = (mode == 0)
                        ? (((size_t)b * 16 + h) * 2048 + s) * 64 + d
                        : (((size_t)b * 16 + h) * 64 + d) * 2048 + s;
                    ((unsigned short*)outv)[idx] = f2bf(v);
                }
            }
        }
    }
}

// flash attention: grid (S/128, H, B), 4 waves, wave owns 32 q-rows; all operands bf16 from ws
__global__ __launch_bounds__(256, 2)
void attn(const unsigned short* __restrict__ qb,
          const unsigned short* __restrict__ kb,
          const unsigned short* __restrict__ vtb,
          const unsigned char* __restrict__ mb,
          unsigned short* __restrict__ ob)
{
    __shared__ __align__(16) unsigned short Ks[64 * 64];      // [key][d] swizzled
    __shared__ __align__(16) unsigned short Vs[64 * 64];      // [d][key] swizzled
    __shared__ __align__(16) unsigned short Ps[4][2][16][72]; // per-wave P, +8 pad
    const int t = threadIdx.x, lane = t & 63, wv = t >> 6;
    const int quad = lane >> 4, l16 = lane & 15;
    const int b = blockIdx.z, h = blockIdx.y, q0 = blockIdx.x * 128;
    const int bh = b * 16 + h;
    const size_t kvbase = (size_t)bh * 2048 * 64;

    short8 aq[2][2]; // A-operand: A[m=lane&15][k=quad*8+j], 2 chunks over dk=64
#pragma unroll
    for (int mi = 0; mi < 2; mi++)
#pragma unroll
        for (int c = 0; c < 2; c++)
            aq[mi][c] = *(const short8*)&qb[kvbase + (size_t)(q0 + wv * 32 + mi * 16 + l16) * 64 + c * 32 + quad * 8];

    floatx4 O[2][4] = {};
    float mrun[2][4], lrun[2][4];
#pragma unroll
    for (int mi = 0; mi < 2; mi++)
#pragma unroll
        for (int r = 0; r < 4; r++) { mrun[mi][r] = -1e30f; lrun[mi][r] = 0.f; }

    for (int kt0 = 0; kt0 < 2048; kt0 += 64) {
#pragma unroll
        for (int s = 0; s < 2; s++) {
            int e = t + s * 256;
            int row = e >> 3, c = e & 7;
            int slot = c ^ (row & 7);
            *(short8*)&Ks[row * 64 + slot * 8] =
                *(const short8*)&kb[kvbase + (size_t)(kt0 + row) * 64 + c * 8];
            *(short8*)&Vs[row * 64 + slot * 8] =
                *(const short8*)&vtb[kvbase + (size_t)row * 2048 + kt0 + c * 8];
        }
        __syncthreads();

        short8 bk[4][2]; // B[k=d][n=key] from Ks[key][d]
#pragma unroll
        for (int j = 0; j < 4; j++)
#pragma unroll
            for (int c = 0; c < 2; c++)
                bk[j][c] = *(const short8*)&Ks[(j * 16 + l16) * 64 + (((c * 4 + quad) ^ (l16 & 7)) * 8)];

#pragma unroll
        for (int mi = 0; mi < 2; mi++) {
            floatx4 sc[4];
#pragma unroll
            for (int j = 0; j < 4; j++) {
                floatx4 z = {0.f, 0.f, 0.f, 0.f};
                z = __builtin_amdgcn_mfma_f32_16x16x32_bf16(aq[mi][0], bk[j][0], z, 0, 0, 0);
                z = __builtin_amdgcn_mfma_f32_16x16x32_bf16(aq[mi][1], bk[j][1], z, 0, 0, 0);
                sc[j] = z;
            }
            float sv[4][4];
#pragma unroll
            for (int r = 0; r < 4; r++) {
                int qr = q0 + wv * 32 + mi * 16 + quad * 4 + r;
                unsigned long long mrow =
                    *(const unsigned long long*)(mb + ((size_t)b * 2048 + qr) * 256 + (kt0 >> 3));
#pragma unroll
                for (int j = 0; j < 4; j++)
                    sv[j][r] = ((mrow >> (j * 16 + l16)) & 1ull) ? sc[j][r] * 0.125f : 1e-11f;
            }
            float rmax[4];
#pragma unroll
            for (int r = 0; r < 4; r++) {
                float m_ = fmaxf(fmaxf(sv[0][r], sv[1][r]), fmaxf(sv[2][r], sv[3][r]));
                m_ = fmaxf(m_, __shfl_xor(m_, 1, 64));
                m_ = fmaxf(m_, __shfl_xor(m_, 2, 64));
                m_ = fmaxf(m_, __shfl_xor(m_, 4, 64));
                m_ = fmaxf(m_, __shfl_xor(m_, 8, 64));
                rmax[r] = m_;
            }
            float alpha[4];
#pragma unroll
            for (int r = 0; r < 4; r++) {
                float mn = fmaxf(mrun[mi][r], rmax[r]);
                alpha[r] = __expf(mrun[mi][r] - mn);
                mrun[mi][r] = mn;
            }
            float rsum[4] = {0.f, 0.f, 0.f, 0.f};
#pragma unroll
            for (int j = 0; j < 4; j++)
#pragma unroll
                for (int r = 0; r < 4; r++) {
                    float p = __expf(sv[j][r] - mrun[mi][r]);
                    rsum[r] += p;
                    Ps[wv][mi][quad * 4 + r][j * 16 + l16] = f2bf(p);
                }
#pragma unroll
            for (int r = 0; r < 4; r++) {
                float s_ = rsum[r];
                s_ += __shfl_xor(s_, 1, 64);
                s_ += __shfl_xor(s_, 2, 64);
                s_ += __shfl_xor(s_, 4, 64);
                s_ += __shfl_xor(s_, 8, 64);
                lrun[mi][r] = lrun[mi][r] * alpha[r] + s_;
            }
#pragma unroll
            for (int j = 0; j < 4; j++)
#pragma unroll
                for (int r = 0; r < 4; r++)
                    O[mi][j][r] *= alpha[r];
        }

        __syncthreads();

        short8 bv[4][2]; // B[k=key][n=d] from Vs[d][key]
#pragma unroll
        for (int j = 0; j < 4; j++)
#pragma unroll
            for (int c = 0; c < 2; c++)
                bv[j][c] = *(const short8*)&Vs[(j * 16 + l16) * 64 + (((c * 4 + quad) ^ (l16 & 7)) * 8)];
#pragma unroll
        for (int mi = 0; mi < 2; mi++) {
            short8 ap[2];
#pragma unroll
            for (int c = 0; c < 2; c++)
                ap[c] = *(const short8*)&Ps[wv][mi][l16][c * 32 + quad * 8];
#pragma unroll
            for (int j = 0; j < 4; j++) {
                O[mi][j] = __builtin_amdgcn_mfma_f32_16x16x32_bf16(ap[0], bv[j][0], O[mi][j], 0, 0, 0);
                O[mi][j] = __builtin_amdgcn_mfma_f32_16x16x32_bf16(ap[1], bv[j][1], O[mi][j], 0, 0, 0);
            }
        }
        __syncthreads();
    }

#pragma unroll
    for (int mi = 0; mi < 2; mi++)
#pragma unroll
        for (int j = 0; j < 4; j++)
#pragma unroll
            for (int r = 0; r < 4; r++) {
                int qr = q0 + wv * 32 + mi * 16 + quad * 4 + r;
                float v = O[mi][j][r] / lrun[mi][r];
                ob[((size_t)b * 2048 + qr) * 1024 + h * 64 + j * 16 + l16] = f2bf(v);
            }
}

// pack mask int32 -> bits (16 ints -> u16)
__global__ void mask_pack(const int* __restrict__ m, unsigned short* __restrict__ o, int n16)
{
    int i = blockIdx.x * blockDim.x + threadIdx.x;
    if (i < n16) {
        const int4* p = (const int4*)(m + (size_t)i * 16);
        unsigned int bits = 0;
#pragma unroll
        for (int j = 0; j < 4; j++) {
            int4 v = p[j];
            bits |= (v.x != 0 ? 1u : 0u) << (j * 4 + 0);
            bits |= (v.y != 0 ? 1u : 0u) << (j * 4 + 1);
            bits |= (v.z != 0 ? 1u : 0u) << (j * 4 + 2);
            bits |= (v.w != 0 ? 1u : 0u) << (j * 4 + 3);
        }
        o[i] = (unsigned short)bits;
    }
}

extern "C" void kernel_launch(void* const* d_in, const int* in_sizes, int n_in,
                              void* d_out, int out_size, void* d_ws, size_t ws_size,
                              hipStream_t stream)
{
    // All float tensors are f32 per the reference; mask is int32; output f32.
    const float* query = (const float*)d_in[0];
    const float* key   = (const float*)d_in[1];
    const float* value = (const float*)d_in[2];
    const int*   mask  = (const int*)d_in[3];
    const float* wq = (const float*)d_in[4];
    const float* bq = (const float*)d_in[5];
    const float* wk = (const float*)d_in[6];
    const float* bk = (const float*)d_in[7];
    const float* wv = (const float*)d_in[8];
    const float* bv = (const float*)d_in[9];
    const float* wo = (const float*)d_in[10];
    const float* bo = (const float*)d_in[11];

    // ws: qb 0-16MB | kb 16-32MB | ob 32-48MB   (bf16 intermediates)
    // d_out (32MB f32): vtb bf16 [0,16MB) + packed mask [16MB,18MB) — both dead
    // before the final GEMM overwrites d_out.
    char* ws = (char*)d_ws;
    const size_t T = 16777216;
    unsigned short* qb  = (unsigned short*)(ws);
    unsigned short* kb  = (unsigned short*)(ws + T);
    unsigned short* ob  = (unsigned short*)(ws + 2 * T);
    unsigned short* vtb = (unsigned short*)d_out;
    unsigned char*  mb  = (unsigned char*)d_out + T;

    mask_pack<<<dim3(4096), 256, 0, stream>>>(mask, (unsigned short*)mb, 1048576);

    dim3 g(64, 8); // M/128, N/128
    gemm_bt<true><<<g, 256, 0, stream>>>(query, wq, bq, qb,  8192, 1024, 1024, 0);
    gemm_bt<true><<<g, 256, 0, stream>>>(key,   wk, bk, kb,  8192, 1024, 1024, 0);
    gemm_bt<true><<<g, 256, 0, stream>>>(value, wv, bv, vtb, 8192, 1024, 1024, 1);

    attn<<<dim3(16, 16, 4), 256, 0, stream>>>(qb, kb, vtb, mb, ob);

    gemm_bt<false><<<g, 256, 0, stream>>>(ob, wo, bo, d_out, 8192, 1024, 1024, 2);
}

// Round 5
// 554.670 us; speedup vs baseline: 1.3309x; 1.3309x over previous
//
#include <hip/hip_runtime.h>

typedef __attribute__((ext_vector_type(8))) short short8;
typedef __attribute__((ext_vector_type(4))) float floatx4;

__device__ inline unsigned short f2bf(float f) {
    union { float f; unsigned int i; } c; c.f = f;
    unsigned int x = c.i;
    unsigned int r = x + 0x7fffu + ((x >> 16) & 1u);
    return (unsigned short)(r >> 16);
}

// async 16B global->LDS; lds base wave-uniform, lane l lands at base + l*16
__device__ inline void gl_lds16(const unsigned short* g, unsigned short* lds_uniform) {
    __builtin_amdgcn_global_load_lds(
        (const __attribute__((address_space(1))) void*)g,
        (__attribute__((address_space(3))) void*)lds_uniform,
        16, 0, 0);
}

// f32 -> bf16 elementwise, 8 elems/thread
__global__ void cvt_bf16(const float* __restrict__ in, unsigned short* __restrict__ out, int n8)
{
    int i = blockIdx.x * blockDim.x + threadIdx.x;
    if (i < n8) {
        const float4* p = (const float4*)(in + (size_t)i * 8);
        float4 a = p[0], b = p[1];
        short8 v;
        v[0] = (short)f2bf(a.x); v[1] = (short)f2bf(a.y);
        v[2] = (short)f2bf(a.z); v[3] = (short)f2bf(a.w);
        v[4] = (short)f2bf(b.x); v[5] = (short)f2bf(b.y);
        v[6] = (short)f2bf(b.z); v[7] = (short)f2bf(b.w);
        *(short8*)(out + (size_t)i * 8) = v;
    }
}

// pack mask int32 -> bits (16 ints -> u16)
__global__ void mask_pack(const int* __restrict__ m, unsigned short* __restrict__ o, int n16)
{
    int i = blockIdx.x * blockDim.x + threadIdx.x;
    if (i < n16) {
        const int4* p = (const int4*)(m + (size_t)i * 16);
        unsigned int bits = 0;
#pragma unroll
        for (int j = 0; j < 4; j++) {
            int4 v = p[j];
            bits |= (v.x != 0 ? 1u : 0u) << (j * 4 + 0);
            bits |= (v.y != 0 ? 1u : 0u) << (j * 4 + 1);
            bits |= (v.z != 0 ? 1u : 0u) << (j * 4 + 2);
            bits |= (v.w != 0 ? 1u : 0u) << (j * 4 + 3);
        }
        o[i] = (unsigned short)bits;
    }
}

// C = A[M,K] @ W[N,K]^T + bias[N]; A,W bf16; bias f32; MFMA bf16, acc fp32
// mode 0: out bf16 [b][h][s][d]; mode 1: out bf16 [b][h][d][s]; mode 2: out f32 [m][n]
__global__ __launch_bounds__(256, 2)
void gemm_bt(const unsigned short* __restrict__ A,
             const unsigned short* __restrict__ W,
             const float* __restrict__ bias,
             void* __restrict__ outv,
             int M, int N, int K, int mode)
{
    __shared__ __align__(16) unsigned short As[128 * 64]; // LDS[row][slot]=glob[row][slot^(row&7)]
    __shared__ __align__(16) unsigned short Bs[128 * 64];
    const int t = threadIdx.x, lane = t & 63, wv = t >> 6;
    const int quad = lane >> 4, l16 = lane & 15;
    const int m0 = blockIdx.x * 128, n0 = blockIdx.y * 128;
    const int wm = (wv >> 1) * 64, wn = (wv & 1) * 64;

    floatx4 acc[4][4] = {};

    for (int k0 = 0; k0 < K; k0 += 64) {
#pragma unroll
        for (int s = 0; s < 4; s++) {
            int e = t + s * 256;
            int row = e >> 3, slot = e & 7;
            int chunk = slot ^ (row & 7);
            gl_lds16(&A[(size_t)(m0 + row) * K + k0 + chunk * 8], &As[wv * 512 + s * 2048]);
            gl_lds16(&W[(size_t)(n0 + row) * K + k0 + chunk * 8], &Bs[wv * 512 + s * 2048]);
        }
        asm volatile("s_waitcnt vmcnt(0)" ::: "memory");
        __syncthreads();

        short8 af[4][2], bfr[4][2];
#pragma unroll
        for (int i = 0; i < 4; i++)
#pragma unroll
            for (int c = 0; c < 2; c++)
                af[i][c] = *(const short8*)&As[(wm + i * 16 + l16) * 64 + (((c * 4 + quad) ^ (l16 & 7)) * 8)];
#pragma unroll
        for (int j = 0; j < 4; j++)
#pragma unroll
            for (int c = 0; c < 2; c++)
                bfr[j][c] = *(const short8*)&Bs[(wn + j * 16 + l16) * 64 + (((c * 4 + quad) ^ (l16 & 7)) * 8)];

#pragma unroll
        for (int c = 0; c < 2; c++)
#pragma unroll
            for (int i = 0; i < 4; i++)
#pragma unroll
                for (int j = 0; j < 4; j++)
                    acc[i][j] = __builtin_amdgcn_mfma_f32_16x16x32_bf16(af[i][c], bfr[j][c], acc[i][j], 0, 0, 0);
        __syncthreads();
    }

    // C/D layout: col=lane&15, row=quad*4+reg
#pragma unroll
    for (int i = 0; i < 4; i++) {
#pragma unroll
        for (int j = 0; j < 4; j++) {
            int n = n0 + wn + j * 16 + l16;
            float bv = bias[n];
#pragma unroll
            for (int r = 0; r < 4; r++) {
                int m = m0 + wm + i * 16 + quad * 4 + r;
                float v = acc[i][j][r] + bv;
                if (mode == 2) {
                    ((float*)outv)[(size_t)m * N + n] = v;
                } else {
                    int b = m >> 11, s = m & 2047, h = n >> 6, d = n & 63;
                    size_t idx = (mode == 0)
                        ? (((size_t)b * 16 + h) * 2048 + s) * 64 + d
                        : (((size_t)b * 16 + h) * 64 + d) * 2048 + s;
                    ((unsigned short*)outv)[idx] = f2bf(v);
                }
            }
        }
    }
}

// flash attention, static-max softmax (shift-invariant; masked score = 1e-11 per ref)
// grid (S/128, H, B), 4 waves, wave owns 32 q-rows
__global__ __launch_bounds__(256, 4)
void attn(const unsigned short* __restrict__ qb,
          const unsigned short* __restrict__ kb,
          const unsigned short* __restrict__ vtb,
          const unsigned char* __restrict__ mb,
          unsigned short* __restrict__ ob)
{
    __shared__ __align__(16) unsigned short Ks[64 * 64];      // [key][d] swizzled
    __shared__ __align__(16) unsigned short Vs[64 * 64];      // [d][key] swizzled
    __shared__ __align__(16) unsigned short Ps[4][2][16][72]; // per-wave P, +8 pad
    const int t = threadIdx.x, lane = t & 63, wv = t >> 6;
    const int quad = lane >> 4, l16 = lane & 15;
    const int b = blockIdx.z, h = blockIdx.y, q0 = blockIdx.x * 128;
    const int bh = b * 16 + h;
    const size_t kvbase = (size_t)bh * 2048 * 64;
    const float MSH = 10.0f;            // static softmax shift
    const float PM = 4.5399931e-05f;    // expf(1e-11 - 10) to fp32

    short8 aq[2][2]; // A-operand: A[m=lane&15][k=quad*8+j]
#pragma unroll
    for (int mi = 0; mi < 2; mi++)
#pragma unroll
        for (int c = 0; c < 2; c++)
            aq[mi][c] = *(const short8*)&qb[kvbase + (size_t)(q0 + wv * 32 + mi * 16 + l16) * 64 + c * 32 + quad * 8];

    floatx4 O[2][4] = {};
    float lrun[2][4] = {};

    for (int kt0 = 0; kt0 < 2048; kt0 += 64) {
#pragma unroll
        for (int s = 0; s < 2; s++) {
            int e = t + s * 256;
            int row = e >> 3, c = e & 7;
            int slot = c ^ (row & 7);
            *(short8*)&Ks[row * 64 + slot * 8] =
                *(const short8*)&kb[kvbase + (size_t)(kt0 + row) * 64 + c * 8];
            *(short8*)&Vs[row * 64 + slot * 8] =
                *(const short8*)&vtb[kvbase + (size_t)row * 2048 + kt0 + c * 8];
        }
        __syncthreads();

        short8 bk[4][2]; // B[k=d][n=key] from Ks[key][d]
#pragma unroll
        for (int j = 0; j < 4; j++)
#pragma unroll
            for (int c = 0; c < 2; c++)
                bk[j][c] = *(const short8*)&Ks[(j * 16 + l16) * 64 + (((c * 4 + quad) ^ (l16 & 7)) * 8)];

#pragma unroll
        for (int mi = 0; mi < 2; mi++) {
            floatx4 sc[4];
#pragma unroll
            for (int j = 0; j < 4; j++) {
                floatx4 z = {0.f, 0.f, 0.f, 0.f};
                z = __builtin_amdgcn_mfma_f32_16x16x32_bf16(aq[mi][0], bk[j][0], z, 0, 0, 0);
                z = __builtin_amdgcn_mfma_f32_16x16x32_bf16(aq[mi][1], bk[j][1], z, 0, 0, 0);
                sc[j] = z;
            }
            float rsum[4];
#pragma unroll
            for (int r = 0; r < 4; r++) {
                int qr = q0 + wv * 32 + mi * 16 + quad * 4 + r;
                uint2 mrow = *(const uint2*)(mb + ((size_t)b * 2048 + qr) * 256 + (kt0 >> 3));
                float acc_r = 0.f;
#pragma unroll
                for (int j = 0; j < 4; j++) {
                    unsigned int w = (j < 2) ? mrow.x : mrow.y;
                    unsigned int bit = (w >> ((j & 1) * 16 + l16)) & 1u;
                    float p = __expf(fmaf(sc[j][r], 0.125f, -MSH));
                    p = bit ? p : PM;
                    acc_r += p;
                    Ps[wv][mi][quad * 4 + r][j * 16 + l16] = f2bf(p);
                }
                rsum[r] = acc_r;
            }
#pragma unroll
            for (int r = 0; r < 4; r++) {
                float s_ = rsum[r];
                s_ += __shfl_xor(s_, 1, 64);
                s_ += __shfl_xor(s_, 2, 64);
                s_ += __shfl_xor(s_, 4, 64);
                s_ += __shfl_xor(s_, 8, 64);
                lrun[mi][r] += s_;
            }
        }

        // PV: wave-local Ps RAW is in-order in the DS pipe — no barrier needed
        short8 bv[4][2]; // B[k=key][n=d] from Vs[d][key]
#pragma unroll
        for (int j = 0; j < 4; j++)
#pragma unroll
            for (int c = 0; c < 2; c++)
                bv[j][c] = *(const short8*)&Vs[(j * 16 + l16) * 64 + (((c * 4 + quad) ^ (l16 & 7)) * 8)];
#pragma unroll
        for (int mi = 0; mi < 2; mi++) {
            short8 ap[2];
#pragma unroll
            for (int c = 0; c < 2; c++)
                ap[c] = *(const short8*)&Ps[wv][mi][l16][c * 32 + quad * 8];
#pragma unroll
            for (int j = 0; j < 4; j++) {
                O[mi][j] = __builtin_amdgcn_mfma_f32_16x16x32_bf16(ap[0], bv[j][0], O[mi][j], 0, 0, 0);
                O[mi][j] = __builtin_amdgcn_mfma_f32_16x16x32_bf16(ap[1], bv[j][1], O[mi][j], 0, 0, 0);
            }
        }
        __syncthreads();
    }

#pragma unroll
    for (int mi = 0; mi < 2; mi++)
#pragma unroll
        for (int j = 0; j < 4; j++)
#pragma unroll
            for (int r = 0; r < 4; r++) {
                int qr = q0 + wv * 32 + mi * 16 + quad * 4 + r;
                float v = O[mi][j][r] / lrun[mi][r];
                ob[((size_t)b * 2048 + qr) * 1024 + h * 64 + j * 16 + l16] = f2bf(v);
            }
}

extern "C" void kernel_launch(void* const* d_in, const int* in_sizes, int n_in,
                              void* d_out, int out_size, void* d_ws, size_t ws_size,
                              hipStream_t stream)
{
    const float* query = (const float*)d_in[0];
    const float* key   = (const float*)d_in[1];
    const float* value = (const float*)d_in[2];
    const int*   mask  = (const int*)d_in[3];
    const float* wq = (const float*)d_in[4];
    const float* bq = (const float*)d_in[5];
    const float* wk = (const float*)d_in[6];
    const float* bk = (const float*)d_in[7];
    const float* wv = (const float*)d_in[8];
    const float* bv = (const float*)d_in[9];
    const float* wo = (const float*)d_in[10];
    const float* bo = (const float*)d_in[11];

    // ws (48 MB proven safe): S0 | S1 | S2, 16 MB each.
    // d_out (32 MB f32): D0 = vtb bf16 [0,16), D1 = weight-bf16 / packed-mask [16,18).
    // Lifetimes: S0 = cvt-input scratch then ob; S1 = qb then wo_bf16; S2 = kb.
    char* ws = (char*)d_ws;
    const size_t T = 16777216;
    unsigned short* S0 = (unsigned short*)(ws);
    unsigned short* S1 = (unsigned short*)(ws + T);
    unsigned short* S2 = (unsigned short*)(ws + 2 * T);
    unsigned short* D0 = (unsigned short*)d_out;
    unsigned short* D1 = (unsigned short*)((char*)d_out + T);

    dim3 g(64, 8); // M/128, N/128

    // Q = query @ wq^T + bq
    cvt_bf16<<<dim3(4096), 256, 0, stream>>>(query, S0, 1048576);
    cvt_bf16<<<dim3(512),  256, 0, stream>>>(wq, D1, 131072);
    gemm_bt<<<g, 256, 0, stream>>>(S0, D1, bq, S1, 8192, 1024, 1024, 0);
    // K
    cvt_bf16<<<dim3(4096), 256, 0, stream>>>(key, S0, 1048576);
    cvt_bf16<<<dim3(512),  256, 0, stream>>>(wk, D1, 131072);
    gemm_bt<<<g, 256, 0, stream>>>(S0, D1, bk, S2, 8192, 1024, 1024, 0);
    // V (transposed layout)
    cvt_bf16<<<dim3(4096), 256, 0, stream>>>(value, S0, 1048576);
    cvt_bf16<<<dim3(512),  256, 0, stream>>>(wv, D1, 131072);
    gemm_bt<<<g, 256, 0, stream>>>(S0, D1, bv, D0, 8192, 1024, 1024, 1);

    mask_pack<<<dim3(4096), 256, 0, stream>>>(mask, D1, 1048576);

    attn<<<dim3(16, 16, 4), 256, 0, stream>>>(S1, S2, D0, (const unsigned char*)D1, S0);

    // out = ob @ wo^T + bo  (f32 output)
    cvt_bf16<<<dim3(512), 256, 0, stream>>>(wo, S1, 131072);
    gemm_bt<<<g, 256, 0, stream>>>(S0, S1, bo, d_out, 8192, 1024, 1024, 2);
}

// Round 6
// 530.233 us; speedup vs baseline: 1.3922x; 1.0461x over previous
//
#include <hip/hip_runtime.h>

typedef __attribute__((ext_vector_type(8))) short short8;
typedef __attribute__((ext_vector_type(4))) float floatx4;

__device__ inline unsigned short f2bf(float f) {
    union { float f; unsigned int i; } c; c.f = f;
    unsigned int x = c.i;
    unsigned int r = x + 0x7fffu + ((x >> 16) & 1u);
    return (unsigned short)(r >> 16);
}

// pack two f32 -> two bf16 (RNE); 1 inst on gfx950, 10-op fallback otherwise
__device__ inline unsigned int pk_bf16(float lo, float hi) {
#if __has_builtin(__builtin_amdgcn_cvt_pk_bf16_f32)
    auto pk = __builtin_amdgcn_cvt_pk_bf16_f32(lo, hi);
    return __builtin_bit_cast(unsigned int, pk);
#else
    return (unsigned int)f2bf(lo) | ((unsigned int)f2bf(hi) << 16);
#endif
}

// async 16B global->LDS; lds base wave-uniform, lane l lands at base + l*16
__device__ inline void gl_lds16(const unsigned short* g, unsigned short* lds_uniform) {
    __builtin_amdgcn_global_load_lds(
        (const __attribute__((address_space(1))) void*)g,
        (__attribute__((address_space(3))) void*)lds_uniform,
        16, 0, 0);
}

// f32 -> bf16 elementwise, 8 elems/thread
__global__ void cvt_bf16(const float* __restrict__ in, unsigned short* __restrict__ out, int n8)
{
    int i = blockIdx.x * blockDim.x + threadIdx.x;
    if (i < n8) {
        const float4* p = (const float4*)(in + (size_t)i * 8);
        float4 a = p[0], b = p[1];
        short8 v;
        v[0] = (short)f2bf(a.x); v[1] = (short)f2bf(a.y);
        v[2] = (short)f2bf(a.z); v[3] = (short)f2bf(a.w);
        v[4] = (short)f2bf(b.x); v[5] = (short)f2bf(b.y);
        v[6] = (short)f2bf(b.z); v[7] = (short)f2bf(b.w);
        *(short8*)(out + (size_t)i * 8) = v;
    }
}

// pack mask int32 -> bits (16 ints -> u16)
__global__ void mask_pack(const int* __restrict__ m, unsigned short* __restrict__ o, int n16)
{
    int i = blockIdx.x * blockDim.x + threadIdx.x;
    if (i < n16) {
        const int4* p = (const int4*)(m + (size_t)i * 16);
        unsigned int bits = 0;
#pragma unroll
        for (int j = 0; j < 4; j++) {
            int4 v = p[j];
            bits |= (v.x != 0 ? 1u : 0u) << (j * 4 + 0);
            bits |= (v.y != 0 ? 1u : 0u) << (j * 4 + 1);
            bits |= (v.z != 0 ? 1u : 0u) << (j * 4 + 2);
            bits |= (v.w != 0 ? 1u : 0u) << (j * 4 + 3);
        }
        o[i] = (unsigned short)bits;
    }
}

// C = A[M,K] @ W[N,K]^T + bias[N]; A,W bf16; bias f32; MFMA bf16, acc fp32
// mode 0: out bf16 [b][h][s][d]; mode 1: out bf16 [b][h][d][s]; mode 2: out f32 [m][n]
__global__ __launch_bounds__(256, 2)
void gemm_bt(const unsigned short* __restrict__ A,
             const unsigned short* __restrict__ W,
             const float* __restrict__ bias,
             void* __restrict__ outv,
             int M, int N, int K, int mode)
{
    __shared__ __align__(16) unsigned short As[128 * 64]; // LDS[row][slot]=glob[row][slot^(row&7)]
    __shared__ __align__(16) unsigned short Bs[128 * 64];
    const int t = threadIdx.x, lane = t & 63, wv = t >> 6;
    const int quad = lane >> 4, l16 = lane & 15;
    const int m0 = blockIdx.x * 128, n0 = blockIdx.y * 128;
    const int wm = (wv >> 1) * 64, wn = (wv & 1) * 64;

    floatx4 acc[4][4] = {};

    for (int k0 = 0; k0 < K; k0 += 64) {
#pragma unroll
        for (int s = 0; s < 4; s++) {
            int e = t + s * 256;
            int row = e >> 3, slot = e & 7;
            int chunk = slot ^ (row & 7);
            gl_lds16(&A[(size_t)(m0 + row) * K + k0 + chunk * 8], &As[wv * 512 + s * 2048]);
            gl_lds16(&W[(size_t)(n0 + row) * K + k0 + chunk * 8], &Bs[wv * 512 + s * 2048]);
        }
        asm volatile("s_waitcnt vmcnt(0)" ::: "memory");
        __syncthreads();

        short8 af[4][2], bfr[4][2];
#pragma unroll
        for (int i = 0; i < 4; i++)
#pragma unroll
            for (int c = 0; c < 2; c++)
                af[i][c] = *(const short8*)&As[(wm + i * 16 + l16) * 64 + (((c * 4 + quad) ^ (l16 & 7)) * 8)];
#pragma unroll
        for (int j = 0; j < 4; j++)
#pragma unroll
            for (int c = 0; c < 2; c++)
                bfr[j][c] = *(const short8*)&Bs[(wn + j * 16 + l16) * 64 + (((c * 4 + quad) ^ (l16 & 7)) * 8)];

#pragma unroll
        for (int c = 0; c < 2; c++)
#pragma unroll
            for (int i = 0; i < 4; i++)
#pragma unroll
                for (int j = 0; j < 4; j++)
                    acc[i][j] = __builtin_amdgcn_mfma_f32_16x16x32_bf16(af[i][c], bfr[j][c], acc[i][j], 0, 0, 0);
        __syncthreads();
    }

    // C/D layout: col=lane&15, row=quad*4+reg
#pragma unroll
    for (int i = 0; i < 4; i++) {
#pragma unroll
        for (int j = 0; j < 4; j++) {
            int n = n0 + wn + j * 16 + l16;
            float bv = bias[n];
#pragma unroll
            for (int r = 0; r < 4; r++) {
                int m = m0 + wm + i * 16 + quad * 4 + r;
                float v = acc[i][j][r] + bv;
                if (mode == 2) {
                    ((float*)outv)[(size_t)m * N + n] = v;
                } else {
                    int b = m >> 11, s = m & 2047, h = n >> 6, d = n & 63;
                    size_t idx = (mode == 0)
                        ? (((size_t)b * 16 + h) * 2048 + s) * 64 + d
                        : (((size_t)b * 16 + h) * 64 + d) * 2048 + s;
                    ((unsigned short*)outv)[idx] = f2bf(v);
                }
            }
        }
    }
}

// flash attention, static-max softmax; 1D grid: bh = blockIdx.x & 63 (XCD-local),
// qtile = blockIdx.x >> 6; 4 waves, wave owns 32 q-rows
__global__ __launch_bounds__(256, 4)
void attn(const unsigned short* __restrict__ qb,
          const unsigned short* __restrict__ kb,
          const unsigned short* __restrict__ vtb,
          const unsigned char* __restrict__ mb,
          unsigned short* __restrict__ ob)
{
    __shared__ __align__(16) unsigned short Ks[64 * 64];      // [key][d] swizzled
    __shared__ __align__(16) unsigned short Vs[64 * 64];      // [d][key] swizzled
    __shared__ __align__(16) unsigned short Ps[4][2][16][72]; // per-wave P, +8 pad
    const int t = threadIdx.x, lane = t & 63, wv = t >> 6;
    const int quad = lane >> 4, l16 = lane & 15;
    const int bh = blockIdx.x & 63;           // same bh -> same XCD (mod-8 invariant)
    const int b = bh >> 4, h = bh & 15;
    const int q0 = (blockIdx.x >> 6) * 128;
    const size_t kvbase = (size_t)bh * 2048 * 64;
    // p = exp(s/8 - 10) = exp2(s*0.125*log2e - 10*log2e)
    const float K1 = 0.1803368801e0f;         // 0.125 * log2(e)
    const float K2 = -14.4269504089f;         // -10 * log2(e)
    const float PM = 4.5399931e-05f;          // exp(1e-11 - 10)

    short8 aq[2][2]; // A-operand: A[m=lane&15][k=quad*8+j]
#pragma unroll
    for (int mi = 0; mi < 2; mi++)
#pragma unroll
        for (int c = 0; c < 2; c++)
            aq[mi][c] = *(const short8*)&qb[kvbase + (size_t)(q0 + wv * 32 + mi * 16 + l16) * 64 + c * 32 + quad * 8];

    floatx4 O[2][4] = {};
    float lrun[2][4] = {};

    for (int kt0 = 0; kt0 < 2048; kt0 += 64) {
#pragma unroll
        for (int s = 0; s < 2; s++) {
            int e = t + s * 256;
            int row = e >> 3, slot = e & 7;
            int chunk = slot ^ (row & 7);
            gl_lds16(&kb[kvbase + (size_t)(kt0 + row) * 64 + chunk * 8], &Ks[wv * 512 + s * 2048]);
            gl_lds16(&vtb[kvbase + (size_t)row * 2048 + kt0 + chunk * 8], &Vs[wv * 512 + s * 2048]);
        }
        asm volatile("s_waitcnt vmcnt(0)" ::: "memory");
        __syncthreads();

        short8 bk[4][2]; // B[k=d][n=key] from Ks[key][d]
#pragma unroll
        for (int j = 0; j < 4; j++)
#pragma unroll
            for (int c = 0; c < 2; c++)
                bk[j][c] = *(const short8*)&Ks[(j * 16 + l16) * 64 + (((c * 4 + quad) ^ (l16 & 7)) * 8)];

#pragma unroll
        for (int mi = 0; mi < 2; mi++) {
            floatx4 sc[4];
#pragma unroll
            for (int j = 0; j < 4; j++) {
                floatx4 z = {0.f, 0.f, 0.f, 0.f};
                z = __builtin_amdgcn_mfma_f32_16x16x32_bf16(aq[mi][0], bk[j][0], z, 0, 0, 0);
                z = __builtin_amdgcn_mfma_f32_16x16x32_bf16(aq[mi][1], bk[j][1], z, 0, 0, 0);
                sc[j] = z;
            }
            float rsum[4];
#pragma unroll
            for (int r = 0; r < 4; r++) {
                int qr = q0 + wv * 32 + mi * 16 + quad * 4 + r;
                uint2 mrow = *(const uint2*)(mb + ((size_t)b * 2048 + qr) * 256 + (kt0 >> 3));
                float p[4];
                float acc_r = 0.f;
#pragma unroll
                for (int j = 0; j < 4; j++) {
                    unsigned int w = (j < 2) ? mrow.x : mrow.y;
                    unsigned int bit = (w >> ((j & 1) * 16 + l16)) & 1u;
                    float e_ = exp2f(fmaf(sc[j][r], K1, K2));
                    p[j] = bit ? e_ : PM;
                    acc_r += p[j];
                }
                rsum[r] = acc_r;
                unsigned int pk01 = pk_bf16(p[0], p[1]);
                unsigned int pk23 = pk_bf16(p[2], p[3]);
                unsigned short* prow = &Ps[wv][mi][quad * 4 + r][l16];
                prow[0]  = (unsigned short)pk01;
                prow[16] = (unsigned short)(pk01 >> 16);
                prow[32] = (unsigned short)pk23;
                prow[48] = (unsigned short)(pk23 >> 16);
            }
#pragma unroll
            for (int r = 0; r < 4; r++) {
                float s_ = rsum[r];
                s_ += __shfl_xor(s_, 1, 64);
                s_ += __shfl_xor(s_, 2, 64);
                s_ += __shfl_xor(s_, 4, 64);
                s_ += __shfl_xor(s_, 8, 64);
                lrun[mi][r] += s_;
            }
        }

        // PV: wave-local Ps RAW is in-order in the DS pipe — no barrier needed
        short8 bv[4][2]; // B[k=key][n=d] from Vs[d][key]
#pragma unroll
        for (int j = 0; j < 4; j++)
#pragma unroll
            for (int c = 0; c < 2; c++)
                bv[j][c] = *(const short8*)&Vs[(j * 16 + l16) * 64 + (((c * 4 + quad) ^ (l16 & 7)) * 8)];
#pragma unroll
        for (int mi = 0; mi < 2; mi++) {
            short8 ap[2];
#pragma unroll
            for (int c = 0; c < 2; c++)
                ap[c] = *(const short8*)&Ps[wv][mi][l16][c * 32 + quad * 8];
#pragma unroll
            for (int j = 0; j < 4; j++) {
                O[mi][j] = __builtin_amdgcn_mfma_f32_16x16x32_bf16(ap[0], bv[j][0], O[mi][j], 0, 0, 0);
                O[mi][j] = __builtin_amdgcn_mfma_f32_16x16x32_bf16(ap[1], bv[j][1], O[mi][j], 0, 0, 0);
            }
        }
        __syncthreads();
    }

#pragma unroll
    for (int mi = 0; mi < 2; mi++)
#pragma unroll
        for (int j = 0; j < 4; j++)
#pragma unroll
            for (int r = 0; r < 4; r++) {
                int qr = q0 + wv * 32 + mi * 16 + quad * 4 + r;
                float v = O[mi][j][r] / lrun[mi][r];
                ob[((size_t)b * 2048 + qr) * 1024 + h * 64 + j * 16 + l16] = f2bf(v);
            }
}

extern "C" void kernel_launch(void* const* d_in, const int* in_sizes, int n_in,
                              void* d_out, int out_size, void* d_ws, size_t ws_size,
                              hipStream_t stream)
{
    const float* query = (const float*)d_in[0];
    const float* key   = (const float*)d_in[1];
    const float* value = (const float*)d_in[2];
    const int*   mask  = (const int*)d_in[3];
    const float* wq = (const float*)d_in[4];
    const float* bq = (const float*)d_in[5];
    const float* wk = (const float*)d_in[6];
    const float* bk = (const float*)d_in[7];
    const float* wv = (const float*)d_in[8];
    const float* bv = (const float*)d_in[9];
    const float* wo = (const float*)d_in[10];
    const float* bo = (const float*)d_in[11];

    // ws (48 MB): S0 | S1 | S2, 16 MB each.
    // d_out (32 MB f32): D0 = vtb bf16 [0,16), D1 = weight-bf16 / packed-mask [16,18).
    char* ws = (char*)d_ws;
    const size_t T = 16777216;
    unsigned short* S0 = (unsigned short*)(ws);
    unsigned short* S1 = (unsigned short*)(ws + T);
    unsigned short* S2 = (unsigned short*)(ws + 2 * T);
    unsigned short* D0 = (unsigned short*)d_out;
    unsigned short* D1 = (unsigned short*)((char*)d_out + T);

    dim3 g(64, 8); // M/128, N/128

    // Q = query @ wq^T + bq
    cvt_bf16<<<dim3(4096), 256, 0, stream>>>(query, S0, 1048576);
    cvt_bf16<<<dim3(512),  256, 0, stream>>>(wq, D1, 131072);
    gemm_bt<<<g, 256, 0, stream>>>(S0, D1, bq, S1, 8192, 1024, 1024, 0);
    // K
    cvt_bf16<<<dim3(4096), 256, 0, stream>>>(key, S0, 1048576);
    cvt_bf16<<<dim3(512),  256, 0, stream>>>(wk, D1, 131072);
    gemm_bt<<<g, 256, 0, stream>>>(S0, D1, bk, S2, 8192, 1024, 1024, 0);
    // V (transposed layout)
    cvt_bf16<<<dim3(4096), 256, 0, stream>>>(value, S0, 1048576);
    cvt_bf16<<<dim3(512),  256, 0, stream>>>(wv, D1, 131072);
    gemm_bt<<<g, 256, 0, stream>>>(S0, D1, bv, D0, 8192, 1024, 1024, 1);

    mask_pack<<<dim3(4096), 256, 0, stream>>>(mask, D1, 1048576);

    attn<<<dim3(1024), 256, 0, stream>>>(S1, S2, D0, (const unsigned char*)D1, S0);

    // out = ob @ wo^T + bo  (f32 output)
    cvt_bf16<<<dim3(512), 256, 0, stream>>>(wo, S1, 131072);
    gemm_bt<<<g, 256, 0, stream>>>(S0, S1, bo, d_out, 8192, 1024, 1024, 2);
}